// Round 1
// baseline (3735.215 us; speedup 1.0000x reference)
//
#include <hip/hip_runtime.h>
#include <stdint.h>

// ---------------------------------------------------------------------------
// Net_57604101374728: GCN(x3)+BN -> maxpool | 6x belief-prop -> diffpool ->
// dense GCN(x3)+BN -> maxpool -> FC. Full fp32 port of the JAX reference.
//
// RNG: JAX threefry, PARTITIONABLE counter mode (bits = hi^lo of the 2x32
// block over a per-element 64-bit counter). If validation fails with O(1)
// absmax, flip RNG_PARTITIONABLE to 0 (original split-halves scheme).
// ---------------------------------------------------------------------------
#define RNG_PARTITIONABLE 1

constexpr int NN    = 65536;    // total nodes
constexpr int NEDGE = 524288;   // edges
constexpr int NBG   = 64;       // graphs

__constant__ int cQS[6]   = {2,4,8,16,32,64};
__constant__ int cQOFF[6] = {0,2,6,14,30,62};

// ---------------- threefry2x32 (20 rounds) ----------------
__device__ __forceinline__ void tf2x32(uint32_t k0, uint32_t k1, uint32_t x0, uint32_t x1,
                                       uint32_t& o0, uint32_t& o1){
  uint32_t ks[3] = {k0, k1, k0 ^ k1 ^ 0x1BD11BDAu};
  x0 += ks[0]; x1 += ks[1];
  const int RA[4] = {13,15,26,6}, RB[4] = {17,29,16,24};
  #pragma unroll
  for (int i=0;i<5;i++){
    const int* r = (i&1)? RB : RA;
    #pragma unroll
    for (int j=0;j<4;j++){
      x0 += x1;
      x1 = (x1 << r[j]) | (x1 >> (32 - r[j]));
      x1 ^= x0;
    }
    x0 += ks[(i+1)%3];
    x1 += ks[(i+2)%3] + (uint32_t)(i+1);
  }
  o0 = x0; o1 = x1;
}

// ---------------- XLA ErfInv32 (Giles), contraction off ----------------
__device__ __forceinline__ float erfinv32(float xx){
  #pragma clang fp contract(off)
  float w = -log1pf(-xx*xx);
  float p;
  if (w < 5.0f){
    w = w - 2.5f;
    p = 2.81022636e-08f;
    p = 3.43273939e-07f  + p*w;
    p = -3.5233877e-06f  + p*w;
    p = -4.39150654e-06f + p*w;
    p = 0.00021858087f   + p*w;
    p = -0.00125372503f  + p*w;
    p = -0.00417768164f  + p*w;
    p = 0.246640727f     + p*w;
    p = 1.50140941f      + p*w;
  } else {
    w = sqrtf(w) - 3.0f;
    p = -0.000200214257f;
    p = 0.000100950558f  + p*w;
    p = 0.00134934322f   + p*w;
    p = -0.00367342844f  + p*w;
    p = 0.00573950773f   + p*w;
    p = -0.0076224613f   + p*w;
    p = 0.00943887047f   + p*w;
    p = 1.00167406f      + p*w;
    p = 2.83297682f      + p*w;
  }
  return p*xx;
}

// ---------------- CSR construction ----------------
__global__ __launch_bounds__(256) void k_count(const int* __restrict__ src, const int* __restrict__ dst,
                                               int* __restrict__ degi, int* __restrict__ dego){
  int e = blockIdx.x*256 + threadIdx.x;
  if (e >= NEDGE) return;
  atomicAdd(&degi[dst[e]], 1);
  atomicAdd(&dego[src[e]], 1);
}

__global__ __launch_bounds__(256) void k_scan1(const int* __restrict__ deg, int* __restrict__ rp,
                                               int* __restrict__ bsum){
  __shared__ int lds[256];
  int b = blockIdx.x, t = threadIdx.x;
  lds[t] = deg[b*256 + t];
  __syncthreads();
  for (int s=1;s<256;s<<=1){
    int add = (t>=s)? lds[t-s] : 0;
    __syncthreads();
    lds[t] += add;
    __syncthreads();
  }
  rp[b*256 + t + 1] = lds[t];
  if (t==0 && b==0) rp[0] = 0;
  if (t==255) bsum[b] = lds[255];
}

__global__ __launch_bounds__(256) void k_scan2(int* __restrict__ bsum){
  __shared__ int lds[256];
  int t = threadIdx.x;
  lds[t] = bsum[t];
  __syncthreads();
  for (int s=1;s<256;s<<=1){
    int add = (t>=s)? lds[t-s] : 0;
    __syncthreads();
    lds[t] += add;
    __syncthreads();
  }
  bsum[t] = (t==0)? 0 : lds[t-1];
}

__global__ __launch_bounds__(256) void k_scan3(int* __restrict__ rp, const int* __restrict__ bsum){
  int b = blockIdx.x, t = threadIdx.x;
  rp[b*256 + t + 1] += bsum[b];
}

__global__ __launch_bounds__(256) void k_fill(const int* __restrict__ key, const int* __restrict__ rp,
                                              int* __restrict__ cnt, int* __restrict__ colbuf){
  int e = blockIdx.x*256 + threadIdx.x;
  if (e >= NEDGE) return;
  int d = key[e];
  int p = atomicAdd(&cnt[d], 1);
  colbuf[rp[d] + p] = e;             // store edge id (sorted next for determinism)
}

__global__ __launch_bounds__(256) void k_sortrow(const int* __restrict__ rp, int* __restrict__ colbuf,
                                                 const int* __restrict__ other){
  int v = blockIdx.x*256 + threadIdx.x;
  if (v >= NN) return;
  int s0 = rp[v], s1 = rp[v+1];
  for (int i=s0+1;i<s1;i++){         // insertion sort by edge id ascending
    int key = colbuf[i]; int j = i-1;
    while (j>=s0 && colbuf[j]>key){ colbuf[j+1]=colbuf[j]; j--; }
    colbuf[j+1] = key;
  }
  for (int i=s0;i<s1;i++) colbuf[i] = other[colbuf[i]];
}

__global__ __launch_bounds__(256) void k_dinv(const int* __restrict__ degi, float* __restrict__ dinv){
  int v = blockIdx.x*256 + threadIdx.x;
  if (v >= NN) return;
  dinv[v] = 1.0f / sqrtf((float)(degi[v] + 1));   // +1 for self loop
}

// ---------------- stage-1 GCN ----------------
template<int CIN>
__global__ __launch_bounds__(256) void k_mm30(const float* __restrict__ x, const float* __restrict__ w,
                                              float* __restrict__ h, int nrow){
  __shared__ float ws[CIN*30];
  int t = threadIdx.x;
  for (int i=t;i<CIN*30;i+=256) ws[i] = w[i];
  __syncthreads();
  int id = blockIdx.x*256 + t;
  if (id >= nrow*30) return;
  int v = id/30, j = id - v*30;
  const float* xr = x + v*CIN;
  float acc = 0.f;
  #pragma unroll
  for (int k=0;k<CIN;k++) acc += xr[k]*ws[k*30+j];
  h[id] = acc;
}

__global__ __launch_bounds__(256) void k_gcn_agg(const float* __restrict__ h, const int* __restrict__ rp,
    const int* __restrict__ col, const float* __restrict__ dinv, const float* __restrict__ bias,
    float* __restrict__ y){
  int id = blockIdx.x*256 + threadIdx.x;
  if (id >= NN*30) return;
  int v = id/30, j = id - v*30;
  float dv = dinv[v];
  float acc = 0.f;
  int a = rp[v], b = rp[v+1];
  for (int i=a;i<b;i++){
    int s = col[i];
    acc += h[s*30 + j] * (dinv[s]*dv);
  }
  acc += h[id]*(dv*dv);      // self loop appended last (matches JAX concat order)
  y[id] = acc + bias[j];
}

// ---------------- BatchNorm (two-pass, biased var) ----------------
__global__ __launch_bounds__(256) void k_bn_part(const float* __restrict__ x, int nrow,
    const float* __restrict__ mean, int pass, float* __restrict__ part){
  __shared__ float lds[256*31];
  int b = blockIdx.x, t = threadIdx.x;
  int rows = nrow >> 8;              // rows per block (nrow divisible by 256)
  float acc[30];
  #pragma unroll
  for (int f=0;f<30;f++) acc[f] = 0.f;
  for (int r=t; r<rows; r+=256){
    const float* xr = x + (b*rows + r)*30;
    if (pass == 0){
      #pragma unroll
      for (int f=0;f<30;f++) acc[f] += xr[f];
    } else {
      #pragma unroll
      for (int f=0;f<30;f++){ float d = xr[f]-mean[f]; acc[f] += d*d; }
    }
  }
  #pragma unroll
  for (int f=0;f<30;f++) lds[t*31+f] = acc[f];
  __syncthreads();
  for (int s=128;s>0;s>>=1){
    if (t<s){
      #pragma unroll
      for (int f=0;f<30;f++) lds[t*31+f] += lds[(t+s)*31+f];
    }
    __syncthreads();
  }
  if (t<30) part[b*30+t] = lds[t];
}

__global__ void k_bn_red(const float* __restrict__ part, float n, float* __restrict__ out){
  int f = threadIdx.x;
  if (f >= 30) return;
  float s = 0.f;
  for (int b=0;b<256;b++) s += part[b*30+f];
  out[f] = s / n;
}

__global__ __launch_bounds__(256) void k_bn_apply(const float* __restrict__ x, const float* __restrict__ mean,
    const float* __restrict__ var, const float* __restrict__ g, const float* __restrict__ be,
    float* __restrict__ out, int nrow){
  int id = blockIdx.x*256 + threadIdx.x;
  if (id >= nrow*30) return;
  int f = id % 30;
  out[id] = g[f]*(x[id]-mean[f]) * (1.0f/sqrtf(var[f]+1e-5f)) + be[f];
}

// ---------------- belief propagation ----------------
__global__ __launch_bounds__(256) void k_bp_init(float* __restrict__ outp){
  int run = blockIdx.y;
  int q = cQS[run], co = cQOFF[run];
  if ((int)blockIdx.x * 256 >= NN*q) return;
  int idx = blockIdx.x*256 + threadIdx.x;
  uint32_t k0,k1;
  tf2x32(0u, 42u, 0u, (uint32_t)run, k0, k1);          // fold_in(key(42), run)
  uint32_t b0,b1;
#if RNG_PARTITIONABLE
  tf2x32(k0, k1, 0u, (uint32_t)idx, b0, b1);           // counter = (0, idx)
  uint32_t bits = b0 ^ b1;
#else
  int half = (NN*q) >> 1;
  uint32_t x0 = (idx < half) ? (uint32_t)idx : (uint32_t)(idx-half);
  uint32_t x1 = x0 + (uint32_t)half;
  tf2x32(k0, k1, x0, x1, b0, b1);
  uint32_t bits = (idx < half) ? b0 : b1;
#endif
  float f = __uint_as_float((bits>>9) | 0x3F800000u) - 1.0f;   // [0,1)
  const float lo = __uint_as_float(0xBF7FFFFFu);               // nextafter(-1,0)
  float u = fmaxf(lo, f*2.0f + lo);
  float z = __uint_as_float(0x3FB504F3u) * erfinv32(u);        // sqrt(2)*erfinv
  int row = idx / q, c = idx - row*q;
  outp[row*126 + co + c] = z;
}

// column sums, sequential row order (matches XLA-CPU reduce; deterministic)
__global__ __launch_bounds__(64) void k_colsum_part(const float* __restrict__ cur, float* __restrict__ part){
  int run = blockIdx.y, q = cQS[run], co = cQOFF[run];
  int b = blockIdx.x, c = threadIdx.x;
  if (c >= q) return;
  float s = 0.f;
  const float* p = cur + b*256*126 + co + c;
  for (int r=0;r<256;r++) s += p[r*126];
  part[(run*256 + b)*64 + c] = s;
}

__global__ void k_field(const float* __restrict__ part, const float* __restrict__ betas,
                        float* __restrict__ field){
  int id = threadIdx.x;              // 384 threads: 6 runs x 64 cols
  int run = id >> 6, c = id & 63;
  if (c >= cQS[run]) return;
  float s = 0.f;
  for (int b=0;b<256;b++) s += part[(run*256 + b)*64 + c];
  float beta = betas[run];
  field[id] = s * (3.8f*beta/65536.0f);
}

template<int FIRST>
__global__ __launch_bounds__(256) void k_bp_step(const float* cur, float* nxt,
    const int* __restrict__ rp, const int* __restrict__ col,
    const float* __restrict__ field, const float* __restrict__ betas){
  int run = blockIdx.y;
  int q = cQS[run], co = cQOFF[run];
  if ((int)blockIdx.x * 256 >= NN*q) return;
  int idx = blockIdx.x*256 + threadIdx.x;
  int row = idx / q, c = idx - row*q;
  float v;
  if (FIRST){
    v = cur[row*126 + co + c];
  } else {
    float eb = expm1f(betas[run]);
    float acc = 0.f;
    int a = rp[row], b2 = rp[row+1];
    for (int i=a;i<b2;i++){
      int s = col[i];
      acc += log1pf(eb * cur[s*126 + co + c]);
    }
    v = acc - field[run*64 + c];
  }
  // softmax over the q lanes of this row (q | 64, groups wave-aligned)
  float m = v;
  for (int off=q>>1; off; off>>=1) m = fmaxf(m, __shfl_xor(m, off, q));
  float e = expf(v - m);
  float ss = e;
  for (int off=q>>1; off; off>>=1) ss += __shfl_xor(ss, off, q);
  nxt[row*126 + co + c] = e / ss;
}

// ---------------- diff-pool ----------------
__global__ __launch_bounds__(256) void k_s1(const float* __restrict__ cat, const float* __restrict__ pw,
                                            const float* __restrict__ pb, float* __restrict__ s1){
  __shared__ float wl[12600];
  __shared__ float rowb[2][126];
  __shared__ float red[8];
  int t = threadIdx.x;
  for (int i=t;i<12600;i+=256) wl[i] = pw[i];
  int half = t>>7, tl = t&127, wid = t>>6;
  __syncthreads();
  for (int it=0; it<16; ++it){
    int v = blockIdx.x*32 + it*2 + half;
    if (tl < 126) rowb[half][tl] = cat[v*126 + tl];
    __syncthreads();
    float acc = -3.402823466e38f;
    if (tl < 100){
      acc = pb[tl];
      for (int j=0;j<126;j++) acc += rowb[half][j]*wl[j*100+tl];
    }
    float m = acc;
    for (int off=32; off; off>>=1) m = fmaxf(m, __shfl_xor(m, off, 64));
    if ((t&63)==0) red[wid] = m;
    __syncthreads();
    m = fmaxf(red[half*2], red[half*2+1]);
    float e = (tl<100)? expf(acc - m) : 0.f;
    float ss = e;
    for (int off=32; off; off>>=1) ss += __shfl_xor(ss, off, 64);
    if ((t&63)==0) red[4+wid] = ss;
    __syncthreads();
    float stot = red[4+half*2] + red[4+half*2+1];
    if (tl<100) s1[v*100+tl] = e/stot;
    __syncthreads();
  }
}

__global__ __launch_bounds__(256) void k_T(const float* __restrict__ s1, const int* __restrict__ rp,
                                           const int* __restrict__ col, float* __restrict__ T){
  int id = blockIdx.x*256 + threadIdx.x;
  if (id >= NN*100) return;
  int v = id/100, l = id - v*100;
  float acc = 0.f;
  int a = rp[v], b = rp[v+1];
  for (int i=a;i<b;i++) acc += s1[col[i]*100 + l];
  T[id] = acc;
}

__global__ __launch_bounds__(128) void k_p1adj(const float* __restrict__ s1, const float* __restrict__ T,
                                               float* __restrict__ padj){
  int b  = blockIdx.x/25;
  int k0 = (blockIdx.x%25)*4;
  int l  = threadIdx.x;
  const float* s1b = s1 + b*1024*100;
  const float* Tb  = T  + b*1024*100;
  float a0=0.f,a1=0.f,a2=0.f,a3=0.f;
  for (int n=0;n<1024;n++){
    float tv = (l<100)? Tb[n*100+l] : 0.f;
    const float* sr = s1b + n*100 + k0;
    a0 += sr[0]*tv; a1 += sr[1]*tv; a2 += sr[2]*tv; a3 += sr[3]*tv;
  }
  if (l<100){
    float* o = padj + b*10000 + k0*100 + l;
    o[0]=a0; o[100]=a1; o[200]=a2; o[300]=a3;
  }
}

__global__ __launch_bounds__(128) void k_p1x(const float* __restrict__ s1, const float* __restrict__ x13,
                                             float* __restrict__ px){
  int b  = blockIdx.x/25;
  int k0 = (blockIdx.x%25)*4;
  int t = threadIdx.x;
  int j = t>>5, d = t&31;
  float acc = 0.f;
  for (int n=0;n<1024;n++){
    float xv = (d<30)? x13[(b*1024+n)*30 + d] : 0.f;
    acc += s1[(b*1024+n)*100 + k0 + j]*xv;
  }
  if (d<30) px[(b*100 + k0 + j)*30 + d] = acc;
}

// ---------------- stage-2 dense GCN ----------------
__global__ __launch_bounds__(256) void k_dinv2(const float* __restrict__ padj, float* __restrict__ dv){
  int id = blockIdx.x*256 + threadIdx.x;
  if (id >= NBG*100) return;
  const float* r = padj + id*100;
  int k = id % 100;
  float s = 0.f;
  for (int l=0;l<100;l++){
    float v = r[l];
    if (l==k) v += 1.0f;     // A = adj + I
    s += v;
  }
  dv[id] = 1.0f/sqrtf(s);
}

__global__ __launch_bounds__(256) void k_Ank(const float* __restrict__ padj, const float* __restrict__ dv,
                                             float* __restrict__ An){
  int id = blockIdx.x*256 + threadIdx.x;
  if (id >= NBG*10000) return;
  int b = id/10000;
  int rem = id - b*10000;
  int k = rem/100, l = rem - k*100;
  float a = padj[id] + ((k==l)? 1.0f : 0.0f);
  An[id] = (dv[b*100+k]*a)*dv[b*100+l];
}

__global__ __launch_bounds__(256) void k_y2(const float* __restrict__ An, const float* __restrict__ h,
    const float* __restrict__ bias, float* __restrict__ y){
  int id = blockIdx.x*256 + threadIdx.x;
  if (id >= NBG*100*30) return;
  int d = id % 30;
  int bk = id / 30;
  int b = bk / 100;
  const float* Ar = An + bk*100;
  const float* hb = h + b*100*30;
  float acc = 0.f;
  for (int l=0;l<100;l++) acc += Ar[l]*hb[l*30+d];
  y[id] = acc + bias[d];
}

// ---------------- pools + FC ----------------
__global__ __launch_bounds__(64) void k_pool(const float* __restrict__ A, const float* __restrict__ Bv,
    const float* __restrict__ Cv, int rows, float* __restrict__ conv, int coff){
  int id = blockIdx.x*64 + threadIdx.x;
  if (id >= NBG*90) return;
  int b = id/90, j = id - b*90;
  const float* X = (j<30)? A : ((j<60)? Bv : Cv);
  int f = j % 30;
  const float* p = X + (b*rows)*30 + f;
  float m = -3.402823466e38f;
  for (int i=0;i<rows;i++) m = fmaxf(m, p[i*30]);
  conv[b*180 + coff + j] = m;
}

__global__ __launch_bounds__(64) void k_fc(const float* __restrict__ conv,
    const float* __restrict__ w1, const float* __restrict__ b1,
    const float* __restrict__ w2, const float* __restrict__ b2, float* __restrict__ out){
  __shared__ float row[180];
  __shared__ float hid[50];
  int b = blockIdx.x, t = threadIdx.x;
  for (int i=t;i<180;i+=64) row[i] = conv[b*180+i];
  __syncthreads();
  if (t < 50){
    float a = b1[t];
    for (int i=0;i<180;i++) a += row[i]*w1[i*50+t];
    hid[t] = fmaxf(a, 0.f);
  }
  __syncthreads();
  if (t < 6){
    float a = b2[t];
    for (int i=0;i<50;i++) a += hid[i]*w2[i*6+t];
    out[b*6+t] = a;
  }
  if (b==0 && t==63) out[NBG*6] = 0.0f;   // second tuple output: zeros((1,))
}

// ---------------------------------------------------------------------------
extern "C" void kernel_launch(void* const* d_in, const int* in_sizes, int n_in,
                              void* d_out, int out_size, void* d_ws, size_t ws_size,
                              hipStream_t stream)
{
  (void)in_sizes; (void)n_in; (void)out_size; (void)ws_size;
  const float* x   = (const float*)d_in[0];
  const int*   src = (const int*)d_in[1];
  const int*   dst = src + NEDGE;
  const float* w11=(const float*)d_in[3],  *b11=(const float*)d_in[4],  *g11=(const float*)d_in[5],  *be11=(const float*)d_in[6];
  const float* w12=(const float*)d_in[7],  *b12=(const float*)d_in[8],  *g12=(const float*)d_in[9],  *be12=(const float*)d_in[10];
  const float* w13=(const float*)d_in[11], *b13=(const float*)d_in[12], *g13=(const float*)d_in[13], *be13=(const float*)d_in[14];
  const float* w21=(const float*)d_in[15], *b21=(const float*)d_in[16], *g21=(const float*)d_in[17], *be21=(const float*)d_in[18];
  const float* w22=(const float*)d_in[19], *b22=(const float*)d_in[20], *g22=(const float*)d_in[21], *be22=(const float*)d_in[22];
  const float* w23=(const float*)d_in[23], *b23=(const float*)d_in[24], *g23=(const float*)d_in[25], *be23=(const float*)d_in[26];
  const float* betas=(const float*)d_in[27];
  const float* poolw=(const float*)d_in[28], *poolb=(const float*)d_in[29];
  const float* fc1w=(const float*)d_in[30], *fc1b=(const float*)d_in[31];
  const float* fc2w=(const float*)d_in[32], *fc2b=(const float*)d_in[33];
  float* out = (float*)d_out;

  uint8_t* basep = (uint8_t*)d_ws;
  size_t off = 0;
  auto take = [&](size_t bytes)->void*{
    void* p = basep + off;
    off = (off + bytes + 255) & ~(size_t)255;
    return p;
  };
  int* degi    = (int*)take((size_t)NN*4);
  int* dego    = (int*)take((size_t)NN*4);
  int* cntA    = (int*)take((size_t)NN*4);
  int* cntB    = (int*)take((size_t)NN*4);
  int* rp_in   = (int*)take((size_t)(NN+1)*4);
  int* rp_out  = (int*)take((size_t)(NN+1)*4);
  int* bsum    = (int*)take(256*4);
  int* col_in  = (int*)take((size_t)NEDGE*4);
  int* col_out = (int*)take((size_t)NEDGE*4);
  float* dinv  = (float*)take((size_t)NN*4);
  float* hbuf  = (float*)take((size_t)NN*30*4);
  float* tmpY  = (float*)take((size_t)NN*30*4);
  float* X1    = (float*)take((size_t)NN*30*4);
  float* X2    = (float*)take((size_t)NN*30*4);
  float* X3    = (float*)take((size_t)NN*30*4);
  float* bufA  = (float*)take((size_t)NN*126*4);
  float* bufB  = (float*)take((size_t)NN*126*4);
  float* partCS= (float*)take((size_t)6*256*64*4);
  float* fieldv= (float*)take(384*4);
  float* partBN= (float*)take(256*30*4);
  float* meanv = (float*)take(128);
  float* varv  = (float*)take(128);
  float* px    = (float*)take(192000*4);
  float* padj  = (float*)take(640000*4);
  float* An    = (float*)take(640000*4);
  float* dinv2 = (float*)take(6400*4);
  float* h2    = (float*)take(192000*4);
  float* y2    = (float*)take(192000*4);
  float* X21   = (float*)take(192000*4);
  float* X22   = (float*)take(192000*4);
  float* X23   = (float*)take(192000*4);
  float* conv  = (float*)take(64*180*4);

  // ---- CSR setup ----
  hipMemsetAsync(degi, 0, (size_t)NN*4, stream);
  hipMemsetAsync(dego, 0, (size_t)NN*4, stream);
  hipMemsetAsync(cntA, 0, (size_t)NN*4, stream);
  hipMemsetAsync(cntB, 0, (size_t)NN*4, stream);
  k_count<<<2048,256,0,stream>>>(src,dst,degi,dego);
  k_scan1<<<256,256,0,stream>>>(degi, rp_in, bsum);
  k_scan2<<<1,256,0,stream>>>(bsum);
  k_scan3<<<256,256,0,stream>>>(rp_in, bsum);
  k_scan1<<<256,256,0,stream>>>(dego, rp_out, bsum);
  k_scan2<<<1,256,0,stream>>>(bsum);
  k_scan3<<<256,256,0,stream>>>(rp_out, bsum);
  k_fill<<<2048,256,0,stream>>>(dst, rp_in, cntA, col_in);
  k_fill<<<2048,256,0,stream>>>(src, rp_out, cntB, col_out);
  k_sortrow<<<256,256,0,stream>>>(rp_in,  col_in,  src);
  k_sortrow<<<256,256,0,stream>>>(rp_out, col_out, dst);
  k_dinv<<<256,256,0,stream>>>(degi, dinv);

  auto run_bn = [&](const float* yin, float* xout, const float* g, const float* be, int nrow){
    k_bn_part<<<256,256,0,stream>>>(yin, nrow, meanv, 0, partBN);
    k_bn_red<<<1,32,0,stream>>>(partBN, (float)nrow, meanv);
    k_bn_part<<<256,256,0,stream>>>(yin, nrow, meanv, 1, partBN);
    k_bn_red<<<1,32,0,stream>>>(partBN, (float)nrow, varv);
    k_bn_apply<<<(nrow*30)/256,256,0,stream>>>(yin, meanv, varv, g, be, xout, nrow);
  };

  // ---- stage 1: sparse GCN + BN x3 ----
  k_mm30<3><<<7680,256,0,stream>>>(x, w11, hbuf, NN);
  k_gcn_agg<<<7680,256,0,stream>>>(hbuf, rp_in, col_in, dinv, b11, tmpY);
  run_bn(tmpY, X1, g11, be11, NN);
  k_mm30<30><<<7680,256,0,stream>>>(X1, w12, hbuf, NN);
  k_gcn_agg<<<7680,256,0,stream>>>(hbuf, rp_in, col_in, dinv, b12, tmpY);
  run_bn(tmpY, X2, g12, be12, NN);
  k_mm30<30><<<7680,256,0,stream>>>(X2, w13, hbuf, NN);
  k_gcn_agg<<<7680,256,0,stream>>>(hbuf, rp_in, col_in, dinv, b13, tmpY);
  run_bn(tmpY, X3, g13, be13, NN);
  k_pool<<<90,64,0,stream>>>(X1, X2, X3, 1024, conv, 0);

  // ---- belief propagation (6 runs fused per launch) ----
  dim3 gbp(16384, 6);
  k_bp_init<<<gbp,256,0,stream>>>(bufA);
  k_bp_step<1><<<gbp,256,0,stream>>>(bufA, bufA, rp_in, col_in, fieldv, betas);
  float* cur = bufA; float* nxt = bufB;
  for (int it=0; it<10; ++it){
    k_colsum_part<<<dim3(256,6),64,0,stream>>>(cur, partCS);
    k_field<<<1,384,0,stream>>>(partCS, betas, fieldv);
    k_bp_step<0><<<gbp,256,0,stream>>>(cur, nxt, rp_in, col_in, fieldv, betas);
    float* tp = cur; cur = nxt; nxt = tp;
  }
  // final psi (all runs concatenated, stride 126) now in bufA

  // ---- diff-pool ----
  k_s1<<<2048,256,0,stream>>>(bufA, poolw, poolb, bufB);      // s1 [n,100] -> bufB
  k_T<<<25600,256,0,stream>>>(bufB, rp_out, col_out, bufA);   // T = A*s1   -> bufA
  k_p1adj<<<1600,128,0,stream>>>(bufB, bufA, padj);
  k_p1x<<<1600,128,0,stream>>>(bufB, X3, px);
  k_dinv2<<<25,256,0,stream>>>(padj, dinv2);
  k_Ank<<<2500,256,0,stream>>>(padj, dinv2, An);

  // ---- stage 2: dense GCN + BN x3 ----
  auto gcn2 = [&](const float* xin, const float* w, const float* bb, const float* g,
                  const float* be, float* xout){
    k_mm30<30><<<750,256,0,stream>>>(xin, w, h2, NBG*100);
    k_y2<<<750,256,0,stream>>>(An, h2, bb, y2);
    run_bn(y2, xout, g, be, NBG*100);
  };
  gcn2(px,  w21, b21, g21, be21, X21);
  gcn2(X21, w22, b22, g22, be22, X22);
  gcn2(X22, w23, b23, g23, be23, X23);
  k_pool<<<90,64,0,stream>>>(X21, X22, X23, 100, conv, 90);

  // ---- FC head ----
  k_fc<<<64,64,0,stream>>>(conv, fc1w, fc1b, fc2w, fc2b, out);
}